// Round 5
// baseline (529.558 us; speedup 1.0000x reference)
//
#include <hip/hip_runtime.h>
#include <stdint.h>

// SE block, float32: x[32,256,56,56] -> out = x * sigmoid(MLP(mean_hw(x)))
// B=32, CH=256, BOT=32, HW=56*56=3136
#define BATCH 32
#define CH    256
#define BOT   32
#define HW    3136
#define CHUNKS_PER_PLANE 784                            // HW/4 float4 per plane
#define TOTAL_CHUNKS (BATCH * CH * CHUNKS_PER_PLANE)    // 6,422,528
#define SCALE_BLOCKS (TOTAL_CHUNKS / 1024)              // 6272, 4 float4/thread

typedef float vfloat4 __attribute__((ext_vector_type(4)));

// ---------------- Kernel A: pool + (last-block-per-batch) MLP ----------------
// grid = 2048: one wave per (b,c) plane, 4 planes/block, 64 blocks per batch.
// After a block's 4 means are published (threadfence + device-scope atomic
// ticket), the LAST block of each batch computes that batch's h[32] and
// g[256]. No spinning -> no dispatch-order hazard (G16-safe: release =
// fence+atomicAdd, acquire = atomic RMW + fence).
__global__ __launch_bounds__(256) void pool_mlp_kernel(
        const float* __restrict__ x,
        const float* __restrict__ w1, const float* __restrict__ b1,
        const float* __restrict__ w2, const float* __restrict__ b2,
        float* __restrict__ s_out, float* __restrict__ g,
        unsigned int* __restrict__ tickets) {
    const int wave = threadIdx.x >> 6;
    const int lane = threadIdx.x & 63;
    const int bc = blockIdx.x * 4 + wave;   // < 8192
    const int b  = blockIdx.x >> 6;         // batch (64 blocks per batch)

    // ---- pool: mean over this plane ----
    const float4* p4 = (const float4*)(x + (size_t)bc * HW);
    float sum = 0.f;
    #pragma unroll
    for (int i = 0; i < 13; ++i) {          // 13*64 = 832 >= 784
        int idx = lane + i * 64;
        if (idx < CHUNKS_PER_PLANE) {
            float4 v = p4[idx];
            sum += (v.x + v.y) + (v.z + v.w);
        }
    }
    #pragma unroll
    for (int off = 32; off > 0; off >>= 1)
        sum += __shfl_down(sum, off, 64);
    if (lane == 0) s_out[bc] = sum * (1.0f / (float)HW);

    // ---- publish + ticket ----
    __threadfence();          // storing lanes order their s_out write device-wide
    __syncthreads();          // all 4 waves' store+fence complete
    __shared__ int amLast;
    if (threadIdx.x == 0)
        amLast = (atomicAdd(&tickets[b], 1u) == 63u);
    __syncthreads();
    if (!amLast) return;      // block-uniform
    __threadfence();          // acquire: see the other 63 blocks' s_out stores

    // ---- MLP for batch b (256 threads) ----
    __shared__ float s_lds[CH];
    __shared__ float hs[BOT];
    const int t = threadIdx.x;
    s_lds[t] = s_out[b * CH + t];
    __syncthreads();

    // h[o] = relu(b1[o] + dot(s, w1[o,:])); o = t>>3, part = t&7, float4 loads
    {
        const int o = t >> 3;
        const int part = t & 7;
        const float4* w4 = (const float4*)(w1 + o * CH + part * 32);
        const float4* s4 = (const float4*)(s_lds + part * 32);
        float acc = 0.f;
        #pragma unroll
        for (int j = 0; j < 8; ++j) {
            float4 wv = w4[j];
            float4 sv = s4[j];
            acc = fmaf(sv.x, wv.x, acc);
            acc = fmaf(sv.y, wv.y, acc);
            acc = fmaf(sv.z, wv.z, acc);
            acc = fmaf(sv.w, wv.w, acc);
        }
        acc += __shfl_xor(acc, 1, 64);
        acc += __shfl_xor(acc, 2, 64);
        acc += __shfl_xor(acc, 4, 64);
        if (part == 0) hs[o] = fmaxf(acc + b1[o], 0.f);
    }
    __syncthreads();

    // g[b,c] = sigmoid(b2[c] + dot(h, w2[c,:])); c = t
    {
        const float4* w4 = (const float4*)(w2 + t * BOT);
        float acc = b2[t];
        #pragma unroll
        for (int j = 0; j < 8; ++j) {
            float4 wv = w4[j];
            acc = fmaf(hs[j * 4 + 0], wv.x, acc);
            acc = fmaf(hs[j * 4 + 1], wv.y, acc);
            acc = fmaf(hs[j * 4 + 2], wv.z, acc);
            acc = fmaf(hs[j * 4 + 3], wv.w, acc);
        }
        g[b * CH + t] = 1.0f / (1.0f + __expf(-acc));
    }
}

// ---------------- Kernel B: scale, non-temporal stores ----------------
// 4 float4/thread, grid = 6272. NT stores keep `out` from write-allocating
// in L2/L3, so x (fully L3-resident after the pool read) stays resident and
// the re-read stays an L3 hit instead of being evicted mid-kernel.
__global__ __launch_bounds__(256) void scale_kernel(
        const float* __restrict__ x, const float* __restrict__ g,
        float* __restrict__ out) {
    const int base = blockIdx.x * 1024 + threadIdx.x;
    #pragma unroll
    for (int i = 0; i < 4; ++i) {
        const int chunk = base + i * 256;
        const int bc = chunk / CHUNKS_PER_PLANE;   // magic-multiply
        const float gv = g[bc];
        vfloat4 v = ((const vfloat4*)x)[chunk];
        v *= gv;
        __builtin_nontemporal_store(v, (vfloat4*)out + chunk);
    }
}

extern "C" void kernel_launch(void* const* d_in, const int* in_sizes, int n_in,
                              void* d_out, int out_size, void* d_ws, size_t ws_size,
                              hipStream_t stream) {
    const float* x  = (const float*)d_in[0];
    const float* w1 = (const float*)d_in[1];
    const float* b1 = (const float*)d_in[2];
    const float* w2 = (const float*)d_in[3];
    const float* b2 = (const float*)d_in[4];
    float* out = (float*)d_out;

    float* s = (float*)d_ws;                      // 8192 floats
    float* g = s + BATCH * CH;                    // 8192 floats
    unsigned int* tickets = (unsigned int*)(g + BATCH * CH);  // 32 uints

    // tickets are in poisoned ws: zero them on-stream (graph-capture-safe)
    hipMemsetAsync(tickets, 0, BATCH * sizeof(unsigned int), stream);

    pool_mlp_kernel<<<BATCH * CH / 4, 256, 0, stream>>>(x, w1, b1, w2, b2, s, g, tickets);
    scale_kernel  <<<SCALE_BLOCKS, 256, 0, stream>>>(x, g, out);
}